// Round 10
// baseline (181.491 us; speedup 1.0000x reference)
//
#include <hip/hip_runtime.h>
#include <hip/hip_cooperative_groups.h>

namespace cg = cooperative_groups;

#define BB 8
#define NN 512
#define SS 96
#define HH 256
#define NHD 8
#define HDD 32
#define OUTD 4

// bf16 weight region (ushort offsets from ws base)
#define WSB_OFF  0
#define WQB_OFF  65536
#define WAOB_OFF 131072
#define W1B_OFF  196608
#define WO1B_OFF 262144
#define CAST_TOTAL 294912
#define KB_OFF   294912                    // [768][256] bf16 k
#define VTB_OFF  491520                    // [B][256][96] bf16 v-transposed

typedef __attribute__((ext_vector_type(8))) short bf16x8;
typedef __attribute__((ext_vector_type(4))) float f32x4;

__device__ __forceinline__ unsigned short f2bf(float f) {
    unsigned int u = __float_as_uint(f);
    u = (u + 0x7FFFu + ((u >> 16) & 1u)) >> 16;   // RNE
    return (unsigned short)u;
}

__device__ __forceinline__ bf16x8 ldw8(const float* __restrict__ p) {
    float4 a = *(const float4*)p, b = *(const float4*)(p + 4);
    bf16x8 r;
    r[0] = (short)f2bf(a.x); r[1] = (short)f2bf(a.y);
    r[2] = (short)f2bf(a.z); r[3] = (short)f2bf(a.w);
    r[4] = (short)f2bf(b.x); r[5] = (short)f2bf(b.y);
    r[6] = (short)f2bf(b.z); r[7] = (short)f2bf(b.w);
    return r;
}

// ============================================================
// MFMA helpers (validated R4-R9). 16-row A tile in LDS bf16 [16][256],
// 16B-slot XOR swizzle: slot' = slot ^ (row&7).
// Wave w owns output cols [w*NCT*16, (w+1)*NCT*16).
// ============================================================
template<int NCT>
__device__ __forceinline__ void mfma_stage(
    const unsigned short* __restrict__ Asw,
    const unsigned short* __restrict__ Wb,
    int lane, int wave, f32x4 acc[NCT])
{
    const int row = lane & 15, kq = lane >> 4;
    #pragma unroll
    for (int ct = 0; ct < NCT; ++ct) acc[ct] = (f32x4){0.f, 0.f, 0.f, 0.f};
    #pragma unroll 2
    for (int kt = 0; kt < 8; ++kt) {
        const int slot = kt * 4 + kq;
        bf16x8 a = *(const bf16x8*)(Asw + row * 256 + ((slot ^ (row & 7)) << 3));
        #pragma unroll
        for (int ct = 0; ct < NCT; ++ct) {
            const unsigned short* wp =
                Wb + (size_t)((wave * NCT + ct) * 16 + row) * 256 + kt * 32 + kq * 8;
            bf16x8 b = *(const bf16x8*)wp;
            acc[ct] = __builtin_amdgcn_mfma_f32_16x16x32_bf16(a, b, acc[ct], 0, 0, 0);
        }
    }
}

// W fp32 global, converted inline (phase-1 temporal path)
template<int NCT>
__device__ __forceinline__ void mfma_stage_f32w(
    const unsigned short* __restrict__ Asw,
    const float* __restrict__ Wf,
    int lane, int wave, f32x4 acc[NCT])
{
    const int row = lane & 15, kq = lane >> 4;
    #pragma unroll
    for (int ct = 0; ct < NCT; ++ct) acc[ct] = (f32x4){0.f, 0.f, 0.f, 0.f};
    #pragma unroll 2
    for (int kt = 0; kt < 8; ++kt) {
        const int slot = kt * 4 + kq;
        bf16x8 a = *(const bf16x8*)(Asw + row * 256 + ((slot ^ (row & 7)) << 3));
        #pragma unroll
        for (int ct = 0; ct < NCT; ++ct) {
            const float* wp =
                Wf + (size_t)((wave * NCT + ct) * 16 + row) * 256 + kt * 32 + kq * 8;
            bf16x8 b = ldw8(wp);
            acc[ct] = __builtin_amdgcn_mfma_f32_16x16x32_bf16(a, b, acc[ct], 0, 0, 0);
        }
    }
}

template<int NCT, bool RELU>
__device__ __forceinline__ void epi_lds(
    unsigned short* __restrict__ OutSw, const float* __restrict__ bias,
    int lane, int wave, const f32x4 acc[NCT])
{
    const int col0 = lane & 15, rq = lane >> 4;
    #pragma unroll
    for (int ct = 0; ct < NCT; ++ct) {
        const int C = wave * NCT * 16 + ct * 16 + col0;
        const float bb = bias[C];
        const int slot = C >> 3, within = C & 7;
        #pragma unroll
        for (int r = 0; r < 4; ++r) {
            const int R = rq * 4 + r;
            float v = acc[ct][r] + bb;
            if (RELU) v = fmaxf(v, 0.f);
            OutSw[R * 256 + ((slot ^ (R & 7)) << 3) + within] = f2bf(v);
        }
    }
}

template<int NCT>
__device__ __forceinline__ void epi_gbf16(
    unsigned short* __restrict__ Og, const float* __restrict__ bias,
    int lane, int wave, const f32x4 acc[NCT])
{
    const int col0 = lane & 15, rq = lane >> 4;
    #pragma unroll
    for (int ct = 0; ct < NCT; ++ct) {
        const int C = wave * NCT * 16 + ct * 16 + col0;
        const float bb = bias[C];
        #pragma unroll
        for (int r = 0; r < 4; ++r) {
            const int R = rq * 4 + r;
            Og[(size_t)R * 256 + C] = f2bf(acc[ct][r] + bb);
        }
    }
}

// stage fp32 global [16][256] -> LDS bf16 swizzled
template<int NT>
__device__ __forceinline__ void stage_A(
    const float* __restrict__ Ag, unsigned short* __restrict__ Asw, int tid)
{
    #pragma unroll
    for (int ii = 0; ii < 1024 / NT; ++ii) {
        int i = tid + ii * NT;
        int row = i >> 6, c4 = i & 63;
        float4 v = ((const float4*)(Ag + (size_t)row * 256))[c4];
        int col = c4 * 4;
        int slot = col >> 3, half = (col >> 2) & 1;
        ushort4 o;
        o.x = f2bf(v.x); o.y = f2bf(v.y); o.z = f2bf(v.z); o.w = f2bf(v.w);
        *(ushort4*)(Asw + row * 256 + ((slot ^ (row & 7)) << 3) + half * 4) = o;
    }
}

// ============================================================
// ONE cooperative kernel. Grid = 256 blocks x 512 thr (8 waves), 1 block/CU.
// Phase 1: blocks 0..191 temporal k/vT (m=blk>>2, c=blk&3); 192..255 cast.
// grid.sync()
// Phase 2: all blocks: spatial->q->attention->MLP->broadcast (R9-validated).
// ============================================================
__global__ __launch_bounds__(512, 2) void k_fused(
    const float* __restrict__ spatial, const float* __restrict__ temporal,
    const float* __restrict__ Ws, const float* __restrict__ bs,
    const float* __restrict__ Wt, const float* __restrict__ bt,
    const float* __restrict__ Win, const float* __restrict__ bin,
    const float* __restrict__ Wao, const float* __restrict__ bao,
    const float* __restrict__ W1, const float* __restrict__ b1,
    const float* __restrict__ Wo1, const float* __restrict__ bo1,
    const float* __restrict__ Wo2, const float* __restrict__ bo2,
    unsigned short* __restrict__ kb, unsigned short* __restrict__ vtb,
    unsigned short* __restrict__ bfw, float* __restrict__ out)
{
    __shared__ __align__(16) unsigned short A0[16 * 256];
    __shared__ __align__(16) unsigned short MID[16 * 256];
    __shared__ __align__(16) unsigned short Q[16 * 256];
    __shared__ __align__(16) unsigned short P[8][16 * 104];
    __shared__ __align__(16) float H2[16 * 128];
    __shared__ __align__(16) float y[16][OUTD];
    const int tid = threadIdx.x, lane = tid & 63, wave = tid >> 6;
    const int cl = lane & 15, kq = lane >> 4;

    // ================= PHASE 1 =================
    if (blockIdx.x < 192) {
        const int m = blockIdx.x >> 2;
        const int c = blockIdx.x & 3;
        const int r0 = m * 16;
        f32x4 acc[2];
        stage_A<512>(temporal + (size_t)r0 * 256, A0, tid);
        __syncthreads();
        mfma_stage_f32w<2>(A0, Wt, lane, wave, acc);           // tp (redundant x4)
        epi_lds<2, false>(MID, bt, lane, wave, acc);
        __syncthreads();
        f32x4 a1[1];
        if (c < 2) {
            mfma_stage_f32w<1>(MID, Win + (size_t)(256 + c * 128) * 256, lane, wave, a1);
            epi_gbf16<1>(kb + (size_t)r0 * 256 + c * 128, bin + 256 + c * 128,
                         lane, wave, a1);
        } else {
            mfma_stage_f32w<1>(MID, Win + (size_t)(512 + (c - 2) * 128) * 256, lane, wave, a1);
            const int bb_ = r0 / 96, s0 = r0 % 96;
            const int rq = lane >> 4;
            const int Cl = (c - 2) * 128 + wave * 16 + cl;
            const float bv = bin[512 + Cl];
            #pragma unroll
            for (int r = 0; r < 4; ++r) {
                const int R = rq * 4 + r;
                vtb[((size_t)(bb_ * 256 + Cl)) * 96 + s0 + R] = f2bf(a1[0][r] + bv);
            }
        }
    } else {
        // cast: Ws | Win[0:65536] | Wao | W1 | Wo1 -> bfw  (64 blocks)
        int idx = (blockIdx.x - 192) * 512 + tid;
        for (int j4 = idx; j4 < CAST_TOTAL / 4; j4 += 64 * 512) {
            int e = j4 * 4;
            const float* src; int off;
            if (e < 65536)       { src = Ws;  off = e; }
            else if (e < 131072) { src = Win; off = e - 65536; }
            else if (e < 196608) { src = Wao; off = e - 131072; }
            else if (e < 262144) { src = W1;  off = e - 196608; }
            else                 { src = Wo1; off = e - 262144; }
            float4 v = *(const float4*)(src + off);
            ushort4 o;
            o.x = f2bf(v.x); o.y = f2bf(v.y); o.z = f2bf(v.z); o.w = f2bf(v.w);
            *(ushort4*)(bfw + e) = o;
        }
    }

    cg::this_grid().sync();

    // ================= PHASE 2 =================
    const int b = blockIdx.x >> 5;
    const int n0 = (blockIdx.x & 31) * 16;
    const float scale = 0.17677669529663687f;  // 1/sqrt(32)
    f32x4 acc[2];

    // spatial chain: in -> sp -> q (all in LDS)
    stage_A<512>(spatial + (size_t)(b * NN + n0) * 256, A0, tid);
    __syncthreads();
    mfma_stage<2>(A0, bfw + WSB_OFF, lane, wave, acc);
    epi_lds<2, false>(MID, bs, lane, wave, acc);
    __syncthreads();
    mfma_stage<2>(MID, bfw + WQB_OFF, lane, wave, acc);
    epi_lds<2, false>(Q, bin, lane, wave, acc);
    // wave w wrote Q cols [32w,32w+32) and reads head h=w: wave-private.

    // attention: 1 head per wave
    unsigned short* Pw = &P[wave][0];
    {
        const int h = wave;
        const int slotq = h * 4 + kq;
        bf16x8 aq = *(const bf16x8*)(Q + cl * 256 + ((slotq ^ (cl & 7)) << 3));
        f32x4 l[6];
        #pragma unroll
        for (int t = 0; t < 6; ++t) {
            bf16x8 bk = *(const bf16x8*)(kb + (size_t)(b * SS + t * 16 + cl) * 256 + h * 32 + kq * 8);
            l[t] = __builtin_amdgcn_mfma_f32_16x16x32_bf16(aq, bk, (f32x4){0.f,0.f,0.f,0.f}, 0, 0, 0);
        }
        float pr[6][4];
        float sum[4] = {0.f, 0.f, 0.f, 0.f};
        #pragma unroll
        for (int t = 0; t < 6; ++t)
            #pragma unroll
            for (int r = 0; r < 4; ++r) {
                float p = __expf(l[t][r] * scale);   // logits O(0.01): no max needed
                pr[t][r] = p; sum[r] += p;
            }
        #pragma unroll
        for (int r = 0; r < 4; ++r) {
            float s = sum[r];
            s += __shfl_xor(s, 1); s += __shfl_xor(s, 2);
            s += __shfl_xor(s, 4); s += __shfl_xor(s, 8);
            sum[r] = 1.0f / s;
        }
        #pragma unroll
        for (int t = 0; t < 6; ++t)
            #pragma unroll
            for (int r = 0; r < 4; ++r)
                Pw[(kq * 4 + r) * 104 + t * 16 + cl] = f2bf(pr[t][r] * sum[r]);
        f32x4 c0 = (f32x4){0.f,0.f,0.f,0.f}, c1 = (f32x4){0.f,0.f,0.f,0.f};
        #pragma unroll
        for (int ks = 0; ks < 3; ++ks) {
            bf16x8 pa = *(const bf16x8*)(Pw + cl * 104 + ks * 32 + kq * 8);
            bf16x8 v0 = *(const bf16x8*)(vtb + (size_t)(b * 256 + h * 32 + cl) * 96 + ks * 32 + kq * 8);
            bf16x8 v1 = *(const bf16x8*)(vtb + (size_t)(b * 256 + h * 32 + 16 + cl) * 96 + ks * 32 + kq * 8);
            c0 = __builtin_amdgcn_mfma_f32_16x16x32_bf16(pa, v0, c0, 0, 0, 0);
            c1 = __builtin_amdgcn_mfma_f32_16x16x32_bf16(pa, v1, c1, 0, 0, 0);
        }
        #pragma unroll
        for (int dt = 0; dt < 2; ++dt) {
            const f32x4 cc = dt ? c1 : c0;
            const int C = h * 32 + dt * 16 + cl;
            const int slot = C >> 3, within = C & 7;
            #pragma unroll
            for (int r = 0; r < 4; ++r) {
                const int R = kq * 4 + r;
                A0[R * 256 + ((slot ^ (R & 7)) << 3) + within] = f2bf(cc[r]);
            }
        }
    }
    __syncthreads();

    // head MLP
    mfma_stage<2>(A0, bfw + WAOB_OFF, lane, wave, acc);
    epi_lds<2, false>(MID, bao, lane, wave, acc);
    __syncthreads();
    mfma_stage<2>(MID, bfw + W1B_OFF, lane, wave, acc);
    epi_lds<2, true>(A0, b1, lane, wave, acc);
    __syncthreads();
    {
        f32x4 a1[1];
        mfma_stage<1>(A0, bfw + WO1B_OFF, lane, wave, a1);
        const int rq = lane >> 4;
        const int C = wave * 16 + cl;
        const float bb = bo1[C];
        #pragma unroll
        for (int r = 0; r < 4; ++r) {
            const int R = rq * 4 + r;
            H2[R * 128 + C] = fmaxf(a1[0][r] + bb, 0.f);
        }
    }
    __syncthreads();
    if (tid < 64) {
        int r = tid >> 2, o = tid & 3;
        float a = 0.f;
        const float4* w4 = (const float4*)(Wo2 + (size_t)o * 128);
        const float4* h4 = (const float4*)(H2 + r * 128);
        for (int kk = 0; kk < 32; ++kk) {
            float4 w = w4[kk], hv = h4[kk];
            a += hv.x * w.x + hv.y * w.y + hv.z * w.z + hv.w * w.w;
        }
        y[r][o] = a + bo2[o];
    }
    __syncthreads();
    for (int i = tid; i < 16 * SS; i += 512) {
        int s = i >> 4;
        int r = i & 15;
        *(float4*)(out + ((size_t)(b * SS + s) * NN + (n0 + r)) * OUTD) = *(const float4*)y[r];
    }
}

extern "C" void kernel_launch(void* const* d_in, const int* in_sizes, int n_in,
                              void* d_out, int out_size, void* d_ws, size_t ws_size,
                              hipStream_t stream) {
    const float* spatial  = (const float*)d_in[0];
    const float* temporal = (const float*)d_in[1];
    const float* Ws  = (const float*)d_in[2];
    const float* bs  = (const float*)d_in[3];
    const float* Wt  = (const float*)d_in[4];
    const float* bt  = (const float*)d_in[5];
    const float* Win = (const float*)d_in[6];
    const float* bin = (const float*)d_in[7];
    const float* Wao = (const float*)d_in[8];
    const float* bao = (const float*)d_in[9];
    const float* W1  = (const float*)d_in[10];
    const float* b1  = (const float*)d_in[11];
    const float* Wo1 = (const float*)d_in[12];
    const float* bo1 = (const float*)d_in[13];
    const float* Wo2 = (const float*)d_in[14];
    const float* bo2 = (const float*)d_in[15];
    float* out = (float*)d_out;
    unsigned short* wsu = (unsigned short*)d_ws;

    unsigned short* bfw = wsu;
    unsigned short* kb  = wsu + KB_OFF;
    unsigned short* vtb = wsu + VTB_OFF;

    void* args[] = {
        (void*)&spatial, (void*)&temporal,
        (void*)&Ws, (void*)&bs, (void*)&Wt, (void*)&bt,
        (void*)&Win, (void*)&bin, (void*)&Wao, (void*)&bao,
        (void*)&W1, (void*)&b1, (void*)&Wo1, (void*)&bo1,
        (void*)&Wo2, (void*)&bo2,
        (void*)&kb, (void*)&vtb, (void*)&bfw, (void*)&out
    };
    hipLaunchCooperativeKernel((const void*)k_fused, dim3(256), dim3(512),
                               args, 0, stream);
}

// Round 11
// 128.363 us; speedup vs baseline: 1.4139x; 1.4139x over previous
//
#include <hip/hip_runtime.h>

#define BB 8
#define NN 512
#define SS 96
#define HH 256
#define NHD 8
#define HDD 32
#define OUTD 4

// ws layout (ushort offsets from ws base)
#define WQS_OFF  0                          // Wq@Ws      [256][256] bf16
#define WKT_OFF  65536                      // Wk@Wt
#define WVT_OFF  131072                     // Wv@Wt
#define W1AO_OFF 196608                     // W1@Wao
#define WO1B_OFF 262144                     // Wo1 cast   [128][256] bf16
#define FB_OFF   294912                     // fp32 fused biases: bqs|bkt|bvt|b1ao (4*256 f32)
#define KB_OFF   296960                     // [768][256] bf16 k
#define VTB_OFF  (KB_OFF + 196608)          // [B][256][96] bf16 v-transposed
#define QB_OFF   (VTB_OFF + 196608)         // [4096][256] bf16 q

typedef __attribute__((ext_vector_type(8))) short bf16x8;
typedef __attribute__((ext_vector_type(4))) float f32x4;

__device__ __forceinline__ unsigned short f2bf(float f) {
    unsigned int u = __float_as_uint(f);
    u = (u + 0x7FFFu + ((u >> 16) & 1u)) >> 16;   // RNE
    return (unsigned short)u;
}

// ============================================================
// MFMA helpers (validated R4-R9). 16-row A tile in LDS bf16 [16][256],
// 16B-slot XOR swizzle: slot' = slot ^ (row&7).
// Wave w owns output cols [w*NCT*16, (w+1)*NCT*16).
// ============================================================
template<int NCT>
__device__ __forceinline__ void mfma_stage(
    const unsigned short* __restrict__ Asw,
    const unsigned short* __restrict__ Wb,
    int lane, int wave, f32x4 acc[NCT])
{
    const int row = lane & 15, kq = lane >> 4;
    #pragma unroll
    for (int ct = 0; ct < NCT; ++ct) acc[ct] = (f32x4){0.f, 0.f, 0.f, 0.f};
    #pragma unroll 2
    for (int kt = 0; kt < 8; ++kt) {
        const int slot = kt * 4 + kq;
        bf16x8 a = *(const bf16x8*)(Asw + row * 256 + ((slot ^ (row & 7)) << 3));
        #pragma unroll
        for (int ct = 0; ct < NCT; ++ct) {
            const unsigned short* wp =
                Wb + (size_t)((wave * NCT + ct) * 16 + row) * 256 + kt * 32 + kq * 8;
            bf16x8 b = *(const bf16x8*)wp;
            acc[ct] = __builtin_amdgcn_mfma_f32_16x16x32_bf16(a, b, acc[ct], 0, 0, 0);
        }
    }
}

template<int NCT, bool RELU>
__device__ __forceinline__ void epi_lds(
    unsigned short* __restrict__ OutSw, const float* __restrict__ bias,
    int lane, int wave, const f32x4 acc[NCT])
{
    const int col0 = lane & 15, rq = lane >> 4;
    #pragma unroll
    for (int ct = 0; ct < NCT; ++ct) {
        const int C = wave * NCT * 16 + ct * 16 + col0;
        const float bb = bias[C];
        const int slot = C >> 3, within = C & 7;
        #pragma unroll
        for (int r = 0; r < 4; ++r) {
            const int R = rq * 4 + r;
            float v = acc[ct][r] + bb;
            if (RELU) v = fmaxf(v, 0.f);
            OutSw[R * 256 + ((slot ^ (R & 7)) << 3) + within] = f2bf(v);
        }
    }
}

template<int NCT>
__device__ __forceinline__ void epi_gbf16(
    unsigned short* __restrict__ Og, const float* __restrict__ bias,
    int lane, int wave, const f32x4 acc[NCT])
{
    const int col0 = lane & 15, rq = lane >> 4;
    #pragma unroll
    for (int ct = 0; ct < NCT; ++ct) {
        const int C = wave * NCT * 16 + ct * 16 + col0;
        const float bb = bias[C];
        #pragma unroll
        for (int r = 0; r < 4; ++r) {
            const int R = rq * 4 + r;
            Og[(size_t)R * 256 + C] = f2bf(acc[ct][r] + bb);
        }
    }
}

// stage fp32 global [16][256] -> LDS bf16 swizzled
template<int NT>
__device__ __forceinline__ void stage_A(
    const float* __restrict__ Ag, unsigned short* __restrict__ Asw, int tid)
{
    #pragma unroll
    for (int ii = 0; ii < 1024 / NT; ++ii) {
        int i = tid + ii * NT;
        int row = i >> 6, c4 = i & 63;
        float4 v = ((const float4*)(Ag + (size_t)row * 256))[c4];
        int col = c4 * 4;
        int slot = col >> 3, half = (col >> 2) & 1;
        ushort4 o;
        o.x = f2bf(v.x); o.y = f2bf(v.y); o.z = f2bf(v.z); o.w = f2bf(v.w);
        *(ushort4*)(Asw + row * 256 + ((slot ^ (row & 7)) << 3) + half * 4) = o;
    }
}

// ---------------- D1: weight fusion + bias fusion + Wo1 cast ----------------
// blocks [0,128): fused-weight GEMM, m = blk>>5 (0..3), t = blk&31.
//   row i = t*8 + wave, thread computes cols j, j+64, j+128, j+192 (256-dot each, fp32).
// blocks [128,136): cast Wo1 -> bf16.
// blocks [136,264): fused biases, wave handles one of 1024 outputs.
__global__ __launch_bounds__(512) void k_wfuse(
    const float* __restrict__ Ws, const float* __restrict__ bs,
    const float* __restrict__ Wt, const float* __restrict__ bt,
    const float* __restrict__ Win, const float* __restrict__ bin,
    const float* __restrict__ Wao, const float* __restrict__ bao,
    const float* __restrict__ W1, const float* __restrict__ b1,
    const float* __restrict__ Wo1,
    unsigned short* __restrict__ bfw, float* __restrict__ fb)
{
    const int tid = threadIdx.x;
    if (blockIdx.x < 128) {
        const int m = blockIdx.x >> 5, t = blockIdx.x & 31;
        const int i = t * 8 + (tid >> 6);
        const int j = tid & 63;
        const float* A = (m == 0) ? Win : (m == 1) ? (Win + 65536)
                       : (m == 2) ? (Win + 131072) : W1;
        const float* B = (m == 0) ? Ws : (m == 3) ? Wao : Wt;
        float a0 = 0.f, a1 = 0.f, a2 = 0.f, a3 = 0.f;
        const float* Ar = A + (size_t)i * 256;
        #pragma unroll 4
        for (int k = 0; k < 256; ++k) {
            float av = Ar[k];
            const float* Br = B + (size_t)k * 256 + j;
            a0 += av * Br[0];
            a1 += av * Br[64];
            a2 += av * Br[128];
            a3 += av * Br[192];
        }
        unsigned short* dst = bfw + m * 65536 + (size_t)i * 256 + j;
        dst[0]   = f2bf(a0);
        dst[64]  = f2bf(a1);
        dst[128] = f2bf(a2);
        dst[192] = f2bf(a3);
    } else if (blockIdx.x < 136) {
        int idx = (blockIdx.x - 128) * 512 + tid;
        for (int e4 = idx; e4 < 8192; e4 += 8 * 512) {
            int e = e4 * 4;
            float4 v = *(const float4*)(Wo1 + e);
            ushort4 o;
            o.x = f2bf(v.x); o.y = f2bf(v.y); o.z = f2bf(v.z); o.w = f2bf(v.w);
            *(ushort4*)(bfw + WO1B_OFF + e) = o;
        }
    } else {
        // fused biases: bqs = Wq@bs+bq ; bkt = Wk@bt+bk ; bvt = Wv@bt+bv ; b1ao = W1@bao+b1
        const int wave = tid >> 6, lane = tid & 63;
        const int g = (blockIdx.x - 136) * 8 + wave;   // 0..1023
        const int m = g >> 8, j = g & 255;
        const float* Wrow; const float* vec; float add;
        if (m == 0)      { Wrow = Win + (size_t)j * 256;          vec = bs;  add = bin[j]; }
        else if (m == 1) { Wrow = Win + (size_t)(256 + j) * 256;  vec = bt;  add = bin[256 + j]; }
        else if (m == 2) { Wrow = Win + (size_t)(512 + j) * 256;  vec = bt;  add = bin[512 + j]; }
        else             { Wrow = W1 + (size_t)j * 256;           vec = bao; add = b1[j]; }
        float s = 0.f;
        #pragma unroll
        for (int q = 0; q < 4; ++q) s += Wrow[q * 64 + lane] * vec[q * 64 + lane];
        s += __shfl_xor(s, 1);  s += __shfl_xor(s, 2);  s += __shfl_xor(s, 4);
        s += __shfl_xor(s, 8);  s += __shfl_xor(s, 16); s += __shfl_xor(s, 32);
        if (lane == 0) fb[m * 256 + j] = s + add;
    }
}

// ---------------- D2: q / k / vT projections (single fused stage each) ----------------
// blocks [0,256): spatial 16 rows -> q (bf16 global)
// blocks [256,352): temporal, m = (blk-256)>>1, which = blk&1 (0: k, 1: vT)
__global__ __launch_bounds__(512) void k_qkv(
    const float* __restrict__ spatial, const float* __restrict__ temporal,
    const unsigned short* __restrict__ bfw, const float* __restrict__ fb,
    unsigned short* __restrict__ qb, unsigned short* __restrict__ kb,
    unsigned short* __restrict__ vtb)
{
    __shared__ __align__(16) unsigned short A0[16 * 256];
    const int tid = threadIdx.x, lane = tid & 63, wave = tid >> 6;
    f32x4 acc[2];

    if (blockIdx.x < 256) {
        const int r0 = blockIdx.x * 16;
        stage_A<512>(spatial + (size_t)r0 * 256, A0, tid);
        __syncthreads();
        mfma_stage<2>(A0, bfw + WQS_OFF, lane, wave, acc);
        epi_gbf16<2>(qb + (size_t)r0 * 256, fb, lane, wave, acc);          // bqs
    } else {
        const int blk = blockIdx.x - 256;
        const int m = blk >> 1, which = blk & 1;
        const int r0 = m * 16;
        stage_A<512>(temporal + (size_t)r0 * 256, A0, tid);
        __syncthreads();
        if (which == 0) {
            mfma_stage<2>(A0, bfw + WKT_OFF, lane, wave, acc);
            epi_gbf16<2>(kb + (size_t)r0 * 256, fb + 256, lane, wave, acc); // bkt
        } else {
            mfma_stage<2>(A0, bfw + WVT_OFF, lane, wave, acc);
            const int bb_ = r0 / 96, s0 = r0 % 96;
            const int cl = lane & 15, rq = lane >> 4;
            #pragma unroll
            for (int ct = 0; ct < 2; ++ct) {
                const int Cl = wave * 32 + ct * 16 + cl;
                const float bv = fb[512 + Cl];                              // bvt
                #pragma unroll
                for (int r = 0; r < 4; ++r) {
                    const int R = rq * 4 + r;
                    vtb[((size_t)(bb_ * 256 + Cl)) * 96 + s0 + R] = f2bf(acc[ct][r] + bv);
                }
            }
        }
    }
}

// ---------------- D3: attention + fused MLP + broadcast ----------------
// grid B * N/16 = 256 blocks x 512 thr (8 waves). Wave w = head w.
__global__ __launch_bounds__(512) void k_attnmlp(
    const unsigned short* __restrict__ qb, const unsigned short* __restrict__ kb,
    const unsigned short* __restrict__ vtb, const unsigned short* __restrict__ bfw,
    const float* __restrict__ fb,
    const float* __restrict__ bo1, const float* __restrict__ Wo2,
    const float* __restrict__ bo2, float* __restrict__ out)
{
    __shared__ __align__(16) unsigned short A0[16 * 256];      // ctx, bf16 swizzled
    __shared__ __align__(16) unsigned short MID[16 * 256];
    __shared__ __align__(16) unsigned short P[8][16 * 104];    // wave-private, pad 104
    __shared__ __align__(16) float H2[16 * 128];
    __shared__ __align__(16) float y[16][OUTD];
    const int tid = threadIdx.x, lane = tid & 63, wave = tid >> 6;
    const int b = blockIdx.x >> 5;
    const int n0 = (blockIdx.x & 31) * 16;
    const int cl = lane & 15, kq = lane >> 4;
    const float scale = 0.17677669529663687f;  // 1/sqrt(32)
    f32x4 acc[2];

    // ---- attention: 1 head per wave; q/k fragments straight from global (L2) ----
    unsigned short* Pw = &P[wave][0];
    {
        const int h = wave;
        bf16x8 aq = *(const bf16x8*)(qb + (size_t)(b * NN + n0 + cl) * 256 + h * 32 + kq * 8);
        f32x4 l[6];
        #pragma unroll
        for (int t = 0; t < 6; ++t) {
            bf16x8 bk = *(const bf16x8*)(kb + (size_t)(b * SS + t * 16 + cl) * 256 + h * 32 + kq * 8);
            l[t] = __builtin_amdgcn_mfma_f32_16x16x32_bf16(aq, bk, (f32x4){0.f,0.f,0.f,0.f}, 0, 0, 0);
        }
        float pr[6][4];
        float sum[4] = {0.f, 0.f, 0.f, 0.f};
        #pragma unroll
        for (int t = 0; t < 6; ++t)
            #pragma unroll
            for (int r = 0; r < 4; ++r) {
                float p = __expf(l[t][r] * scale);   // logits O(0.01): no max needed
                pr[t][r] = p; sum[r] += p;
            }
        #pragma unroll
        for (int r = 0; r < 4; ++r) {
            float s = sum[r];
            s += __shfl_xor(s, 1); s += __shfl_xor(s, 2);
            s += __shfl_xor(s, 4); s += __shfl_xor(s, 8);
            sum[r] = 1.0f / s;
        }
        #pragma unroll
        for (int t = 0; t < 6; ++t)
            #pragma unroll
            for (int r = 0; r < 4; ++r)
                Pw[(kq * 4 + r) * 104 + t * 16 + cl] = f2bf(pr[t][r] * sum[r]);
        f32x4 c0 = (f32x4){0.f,0.f,0.f,0.f}, c1 = (f32x4){0.f,0.f,0.f,0.f};
        #pragma unroll
        for (int ks = 0; ks < 3; ++ks) {
            bf16x8 pa = *(const bf16x8*)(Pw + cl * 104 + ks * 32 + kq * 8);
            bf16x8 v0 = *(const bf16x8*)(vtb + (size_t)(b * 256 + h * 32 + cl) * 96 + ks * 32 + kq * 8);
            bf16x8 v1 = *(const bf16x8*)(vtb + (size_t)(b * 256 + h * 32 + 16 + cl) * 96 + ks * 32 + kq * 8);
            c0 = __builtin_amdgcn_mfma_f32_16x16x32_bf16(pa, v0, c0, 0, 0, 0);
            c1 = __builtin_amdgcn_mfma_f32_16x16x32_bf16(pa, v1, c1, 0, 0, 0);
        }
        // ctx -> A0 (bf16, swizzled), cols h*32 .. h*32+31 (wave-private)
        #pragma unroll
        for (int dt = 0; dt < 2; ++dt) {
            const f32x4 cc = dt ? c1 : c0;
            const int C = h * 32 + dt * 16 + cl;
            const int slot = C >> 3, within = C & 7;
            #pragma unroll
            for (int r = 0; r < 4; ++r) {
                const int R = kq * 4 + r;
                A0[R * 256 + ((slot ^ (R & 7)) << 3) + within] = f2bf(cc[r]);
            }
        }
    }
    __syncthreads();

    // ---- fused = relu(ctx @ (W1@Wao).T + b1ao) -> MID ----
    mfma_stage<2>(A0, bfw + W1AO_OFF, lane, wave, acc);
    epi_lds<2, true>(MID, fb + 768, lane, wave, acc);   // b1ao
    __syncthreads();
    // ---- h2 = relu(fused @ Wo1.T + bo1) -> H2 (fp32, 128 cols) ----
    {
        f32x4 a1[1];
        mfma_stage<1>(MID, bfw + WO1B_OFF, lane, wave, a1);
        const int rq = lane >> 4;
        const int C = wave * 16 + cl;
        const float bb = bo1[C];
        #pragma unroll
        for (int r = 0; r < 4; ++r) {
            const int R = rq * 4 + r;
            H2[R * 128 + C] = fmaxf(a1[0][r] + bb, 0.f);
        }
    }
    __syncthreads();
    // ---- y = h2 @ Wo2.T + bo2 ----
    if (tid < 64) {
        int r = tid >> 2, o = tid & 3;
        float a = 0.f;
        const float4* w4 = (const float4*)(Wo2 + (size_t)o * 128);
        const float4* h4 = (const float4*)(H2 + r * 128);
        for (int kk = 0; kk < 32; ++kk) {
            float4 w = w4[kk], hv = h4[kk];
            a += hv.x * w.x + hv.y * w.y + hv.z * w.z + hv.w * w.w;
        }
        y[r][o] = a + bo2[o];
    }
    __syncthreads();
    // ---- broadcast: out[b][s][n0+r][:] = y[r] ----
    for (int i = tid; i < 16 * SS; i += 512) {
        int s = i >> 4;
        int r = i & 15;
        *(float4*)(out + ((size_t)(b * SS + s) * NN + (n0 + r)) * OUTD) = *(const float4*)y[r];
    }
}

extern "C" void kernel_launch(void* const* d_in, const int* in_sizes, int n_in,
                              void* d_out, int out_size, void* d_ws, size_t ws_size,
                              hipStream_t stream) {
    const float* spatial  = (const float*)d_in[0];
    const float* temporal = (const float*)d_in[1];
    const float* Ws  = (const float*)d_in[2];
    const float* bs  = (const float*)d_in[3];
    const float* Wt  = (const float*)d_in[4];
    const float* bt  = (const float*)d_in[5];
    const float* Win = (const float*)d_in[6];
    const float* bin = (const float*)d_in[7];
    const float* Wao = (const float*)d_in[8];
    const float* bao = (const float*)d_in[9];
    const float* W1  = (const float*)d_in[10];
    const float* b1  = (const float*)d_in[11];
    const float* Wo1 = (const float*)d_in[12];
    const float* bo1 = (const float*)d_in[13];
    const float* Wo2 = (const float*)d_in[14];
    const float* bo2 = (const float*)d_in[15];
    float* out = (float*)d_out;
    unsigned short* wsu = (unsigned short*)d_ws;

    unsigned short* bfw = wsu;                   // fused bf16 weights
    float* fb = (float*)(wsu + FB_OFF);          // fused fp32 biases
    unsigned short* kb  = wsu + KB_OFF;
    unsigned short* vtb = wsu + VTB_OFF;
    unsigned short* qb  = wsu + QB_OFF;

    hipLaunchKernelGGL(k_wfuse, dim3(264), dim3(512), 0, stream,
                       Ws, bs, Wt, bt, Win, bin, Wao, bao, W1, b1, Wo1,
                       bfw, fb);
    hipLaunchKernelGGL(k_qkv, dim3(352), dim3(512), 0, stream,
                       spatial, temporal, bfw, fb, qb, kb, vtb);
    hipLaunchKernelGGL(k_attnmlp, dim3(256), dim3(512), 0, stream,
                       qb, kb, vtb, bfw, fb, bo1, Wo2, bo2, out);
}